// Round 2
// baseline (473.628 us; speedup 1.0000x reference)
//
#include <hip/hip_runtime.h>
#include <math.h>

typedef float f2 __attribute__((ext_vector_type(2)));
typedef float f4 __attribute__((ext_vector_type(4)));

#define DD 160
#define HH 160
#define WW 160
#define BB 4
#define KK 11
#define RAD 5
#define TH 16
#define TW 16
#define DCH 32
#define NPLANES (DCH + 2 * RAD)   // 42
#define NDCH (DD / DCH)           // 5
#define HALO 26                   // TH + 2*RAD (= cols too)
#define SW 28                     // s row stride (floats); 28%32 spreads banks, 16B-aligns c%4==0
#define TS 18                     // tmp row stride; 18%32 spreads banks, 8B-aligned

struct GaussW { float g[KK]; };

__global__ __launch_bounds__(128)
void ssim3d_kernel(const float* __restrict__ img1,
                   const float* __restrict__ img2,
                   float* __restrict__ out, GaussW gw)
{
    __shared__ float s1[HALO * SW];
    __shared__ float s2[HALO * SW];
    __shared__ float tmp[5][HALO * TS];
    __shared__ float wsum[2];

    const int tid = threadIdx.x;      // 128 threads = 2 waves
    const int xc  = tid & 7;          // output col pair (2xc, 2xc+1)
    const int ty  = tid >> 3;         // output row 0..15

    const int blk = blockIdx.x;
    const int bw = blk % 10;
    const int bh = (blk / 10) % 10;
    const int bd = (blk / 100) % NDCH;
    const int bb = blk / (100 * NDCH);

    const int oh0 = bh * TH, ow0 = bw * TW, od0 = bd * DCH;
    const float* base1 = img1 + (size_t)bb * DD * HH * WW;
    const float* base2 = img2 + (size_t)bb * DD * HH * WW;

    float g[KK];
#pragma unroll
    for (int i = 0; i < KK; ++i) g[i] = gw.g[i];

    // D-ring: slot i -> output plane emitted i planes from now (float2 = 2 W-cols)
    f2 a1[KK], a2[KK], a11[KK], a22[KK], a12[KK];
#pragma unroll
    for (int i = 0; i < KK; ++i) { a1[i]=0.f; a2[i]=0.f; a11[i]=0.f; a22[i]=0.f; a12[i]=0.f; }

    const bool inb_hw = (oh0 >= RAD) && (oh0 + TH + RAD <= HH) &&
                        (ow0 >= RAD) && (ow0 + TW + RAD <= WW);

    f2 lsum = 0.f;

    for (int p = 0; p < NPLANES; ++p) {
        const int d = od0 - RAD + p;
        const bool dval = (d >= 0) && (d < DD);   // block-uniform

        f2 P1 = 0.f, P2 = 0.f, P11 = 0.f, P22 = 0.f, P12 = 0.f;
        if (dval) {
            // ---- stage A: load 26x26 halo of this plane into LDS ----
            const size_t pb = (size_t)d * HH * WW;
            if (inb_hw) {
                const float* q1 = base1 + pb + (size_t)(oh0 - RAD) * WW + (ow0 - RAD);
                const float* q2 = base2 + pb + (size_t)(oh0 - RAD) * WW + (ow0 - RAD);
                for (int e = tid; e < HALO * HALO; e += 128) {
                    int r = e / HALO, c = e - r * HALO;
                    s1[r * SW + c] = q1[r * WW + c];
                    s2[r * SW + c] = q2[r * WW + c];
                }
            } else {
                for (int e = tid; e < HALO * HALO; e += 128) {
                    int r = e / HALO, c = e - r * HALO;
                    int ih = oh0 - RAD + r, iw = ow0 - RAD + c;
                    float v1 = 0.f, v2 = 0.f;
                    if ((unsigned)ih < (unsigned)HH && (unsigned)iw < (unsigned)WW) {
                        size_t ix = pb + (size_t)ih * WW + iw;
                        v1 = base1[ix]; v2 = base2[ix];
                    }
                    s1[r * SW + c] = v1;
                    s2[r * SW + c] = v2;
                }
            }
            __syncthreads();

            // ---- stage B: W-conv of 5 stats, 4-wide per thread, b128 reads ----
            if (tid < 104) {                 // 26 rows x 4 col-quads
                const int r = tid >> 2;
                const int c = (tid & 3) * 4;
                const float* r1 = s1 + r * SW + c;
                const float* r2 = s2 + r * SW + c;
                float A[16], Bv[16];
                *(f4*)&A[0]  = *(const f4*)(r1 + 0);
                *(f4*)&A[4]  = *(const f4*)(r1 + 4);
                *(f4*)&A[8]  = *(const f4*)(r1 + 8);
                *(f4*)&A[12] = *(const f4*)(r1 + 12);
                *(f4*)&Bv[0]  = *(const f4*)(r2 + 0);
                *(f4*)&Bv[4]  = *(const f4*)(r2 + 4);
                *(f4*)&Bv[8]  = *(const f4*)(r2 + 8);
                *(f4*)&Bv[12] = *(const f4*)(r2 + 12);

                float t1[4]  = {0.f,0.f,0.f,0.f};
                float t2[4]  = {0.f,0.f,0.f,0.f};
                float t11[4] = {0.f,0.f,0.f,0.f};
                float t22[4] = {0.f,0.f,0.f,0.f};
                float t12[4] = {0.f,0.f,0.f,0.f};
#pragma unroll
                for (int i = 0; i < 14; ++i) {     // cols c..c+13 feed outputs c..c+3
                    float av = A[i], bv = Bv[i];
                    float aa = av * av, bb = bv * bv, ab = av * bv;
#pragma unroll
                    for (int j = 0; j < 4; ++j) {
                        const int k = i - j;
                        if (k >= 0 && k < KK) {
                            float w = g[k];
                            t1[j]  += w * av;
                            t2[j]  += w * bv;
                            t11[j] += w * aa;
                            t22[j] += w * bb;
                            t12[j] += w * ab;
                        }
                    }
                }
                const int tb = r * TS + c;
#pragma unroll
                for (int j = 0; j < 4; j += 2) {
                    f2 v;
                    v.x = t1[j];  v.y = t1[j+1];  *(f2*)&tmp[0][tb + j] = v;
                    v.x = t2[j];  v.y = t2[j+1];  *(f2*)&tmp[1][tb + j] = v;
                    v.x = t11[j]; v.y = t11[j+1]; *(f2*)&tmp[2][tb + j] = v;
                    v.x = t22[j]; v.y = t22[j+1]; *(f2*)&tmp[3][tb + j] = v;
                    v.x = t12[j]; v.y = t12[j+1]; *(f2*)&tmp[4][tb + j] = v;
                }
            }
            __syncthreads();

            // ---- stage C: H-conv (float2 via b64 taps) ----
#pragma unroll
            for (int k = 0; k < KK; ++k) {
                const float w = g[k];
                const int off = (ty + k) * TS + 2 * xc;
                f2 v;
                v = *(const f2*)&tmp[0][off]; P1  += w * v;
                v = *(const f2*)&tmp[1][off]; P2  += w * v;
                v = *(const f2*)&tmp[2][off]; P11 += w * v;
                v = *(const f2*)&tmp[3][off]; P22 += w * v;
                v = *(const f2*)&tmp[4][off]; P12 += w * v;
            }
            // D scatter into the ring
#pragma unroll
            for (int i = 0; i < KK; ++i) {
                const float w = g[KK - 1 - i];
                a1[i]  += w * P1;
                a2[i]  += w * P2;
                a11[i] += w * P11;
                a22[i] += w * P22;
                a12[i] += w * P12;
            }
        }

        if (p >= 2 * RAD) {   // output plane od = od0 + p - 10 complete in slot 0
            f2 mu1 = a1[0], mu2 = a2[0];
            f2 m11 = mu1 * mu1, m22 = mu2 * mu2, m12 = mu1 * mu2;
            f2 sg1 = a11[0] - m11, sg2 = a22[0] - m22, sg12 = a12[0] - m12;
            const float C1c = 0.0001f, C2c = 0.0009f;
            f2 num = (2.f * m12 + C1c) * (2.f * sg12 + C2c);
            f2 den = (m11 + m22 + C1c) * (sg1 + sg2 + C2c);
            lsum += num / den;
        }
        // shift ring
#pragma unroll
        for (int i = 0; i < KK - 1; ++i) {
            a1[i] = a1[i+1]; a2[i] = a2[i+1]; a11[i] = a11[i+1];
            a22[i] = a22[i+1]; a12[i] = a12[i+1];
        }
        a1[KK-1]=0.f; a2[KK-1]=0.f; a11[KK-1]=0.f; a22[KK-1]=0.f; a12[KK-1]=0.f;
    }

    // ---- reduction: wave shuffle -> LDS -> one atomic per block ----
    float v = lsum.x + lsum.y;
#pragma unroll
    for (int off = 32; off > 0; off >>= 1)
        v += __shfl_down(v, off, 64);
    if ((tid & 63) == 0) wsum[tid >> 6] = v;
    __syncthreads();
    if (tid == 0) {
        const float inv_n = 1.0f / ((float)BB * DD * HH * WW);
        atomicAdd(out, (wsum[0] + wsum[1]) * inv_n);
    }
}

extern "C" void kernel_launch(void* const* d_in, const int* in_sizes, int n_in,
                              void* d_out, int out_size, void* d_ws, size_t ws_size,
                              hipStream_t stream) {
    const float* img1 = (const float*)d_in[0];
    const float* img2 = (const float*)d_in[1];
    float* out = (float*)d_out;

    GaussW gw;
    double gd[KK], sum = 0.0;
    for (int i = 0; i < KK; ++i) {
        double x = (double)(i - KK / 2);
        gd[i] = exp(-(x * x) / (2.0 * 1.5 * 1.5));
        sum += gd[i];
    }
    for (int i = 0; i < KK; ++i) gw.g[i] = (float)(gd[i] / sum);

    hipMemsetAsync(d_out, 0, sizeof(float), stream);

    dim3 grid(BB * NDCH * 10 * 10);   // 2000 blocks
    dim3 block(128);
    hipLaunchKernelGGL(ssim3d_kernel, grid, block, 0, stream,
                       img1, img2, out, gw);
}